// Round 4
// baseline (722.672 us; speedup 1.0000x reference)
//
#include <hip/hip_runtime.h>

#define NROWS 131072          // 64*2048
#define D 64
#define K 512
#define TPB 256
#define NBLOCKS (NROWS/TPB)   // 512 blocks = 2 blocks/CU

#define LOSS_OFF (NROWS*D)    // 8388608
#define PERP_OFF (LOSS_OFF+1)
#define IDX_OFF  (LOSS_OFF+2)

// ws layout: [0]: float wsum; [256B]: int hist[512]; [4096B]: float e2[512]

__global__ __launch_bounds__(64) void vq_norms(
    const float* __restrict__ emb, float* __restrict__ e2)
{
    int k = blockIdx.x * 64 + threadIdx.x;   // grid 8 x 64
    const float* e = emb + (size_t)k * D;
    float s0=0.f,s1=0.f,s2=0.f,s3=0.f;
    #pragma unroll
    for (int d = 0; d < D; d += 4) {
        s0 = fmaf(e[d+0], e[d+0], s0);
        s1 = fmaf(e[d+1], e[d+1], s1);
        s2 = fmaf(e[d+2], e[d+2], s2);
        s3 = fmaf(e[d+3], e[d+3], s3);
    }
    e2[k] = (s0+s1)+(s2+s3);   // same order as rounds 1-3 (absmax 0.0)
}

// One full code (64 floats) staged in NAMED registers — no arrays, no
// possible scratch demotion (rule #20).
struct Code {
    float4 q0,q1,q2,q3,q4,q5,q6,q7,q8,q9,q10,q11,q12,q13,q14,q15;
};

#define LOADC(BUF, kk) do {                                         \
    const float4* _p = ebase + (size_t)(kk) * 16;                   \
    BUF.q0 =_p[0];  BUF.q1 =_p[1];  BUF.q2 =_p[2];  BUF.q3 =_p[3];  \
    BUF.q4 =_p[4];  BUF.q5 =_p[5];  BUF.q6 =_p[6];  BUF.q7 =_p[7];  \
    BUF.q8 =_p[8];  BUF.q9 =_p[9];  BUF.q10=_p[10]; BUF.q11=_p[11]; \
    BUF.q12=_p[12]; BUF.q13=_p[13]; BUF.q14=_p[14]; BUF.q15=_p[15]; \
} while (0)

#define ACC4(V, DD)                         \
    a0 = fmaf(xr[(DD)+0], (V).x, a0);       \
    a1 = fmaf(xr[(DD)+1], (V).y, a1);       \
    a2 = fmaf(xr[(DD)+2], (V).z, a2);       \
    a3 = fmaf(xr[(DD)+3], (V).w, a3);

#define DOTC(BUF, kk) do {                                          \
    float a0=0.f, a1=0.f, a2=0.f, a3=0.f;                           \
    ACC4(BUF.q0,  0)  ACC4(BUF.q1,  4)  ACC4(BUF.q2,  8)           \
    ACC4(BUF.q3,  12) ACC4(BUF.q4,  16) ACC4(BUF.q5,  20)          \
    ACC4(BUF.q6,  24) ACC4(BUF.q7,  28) ACC4(BUF.q8,  32)          \
    ACC4(BUF.q9,  36) ACC4(BUF.q10, 40) ACC4(BUF.q11, 44)          \
    ACC4(BUF.q12, 48) ACC4(BUF.q13, 52) ACC4(BUF.q14, 56)          \
    ACC4(BUF.q15, 60)                                               \
    float dist = fmaf(-2.f, (a0+a1)+(a2+a3), e2n[(kk)]);            \
    if (dist < best) { best = dist; bi = (kk); }                    \
} while (0)

__global__ __launch_bounds__(TPB, 2) void vq_main(
    const float* __restrict__ x, const float* __restrict__ emb,
    const float* __restrict__ e2n,
    float* __restrict__ out, float* __restrict__ wsum, int* __restrict__ whist)
{
    __shared__ int shist[K];
    for (int i = threadIdx.x; i < K; i += TPB) shist[i] = 0;
    __syncthreads();

    const int r = blockIdx.x * TPB + threadIdx.x;

    // row into registers (one contiguous 256B row per thread)
    float xr[D];
    {
        const float4* p = reinterpret_cast<const float4*>(x + (size_t)r * D);
        #pragma unroll
        for (int i = 0; i < D/4; ++i) {
            float4 v = p[i];
            xr[4*i+0]=v.x; xr[4*i+1]=v.y; xr[4*i+2]=v.z; xr[4*i+3]=v.w;
        }
    }

    const float4* ebase = reinterpret_cast<const float4*>(emb);

    float best = 3.4e38f;
    int   bi = 0;

    Code A, B;
    LOADC(A, 0);
    LOADC(B, 1);

    // 256 iterations, 2 codes each: compute Cur, refill Cur with k+2.
    // Loads get a full code of FMAs (256 cyc) x 2-wave interleave to land.
    #pragma clang loop unroll(disable)
    for (int k = 0; k < K; k += 2) {
        DOTC(A, k);
        { int kn = k + 2;  if (kn >= K) kn = 0;  LOADC(A, kn); }
        DOTC(B, k + 1);
        { int kn = k + 3;  if (kn >= K) kn = 0;  LOADC(B, kn); }
    }

    // epilogue: gather code from global (L2-hot), straight-through out,
    // squared-diff accumulation, index, histogram  (bit-identical to R1-3)
    float dsum = 0.f;
    {
        const float4* eq = reinterpret_cast<const float4*>(emb + (size_t)bi * D);
        float4* o = reinterpret_cast<float4*>(out + (size_t)r * D);
        #pragma unroll
        for (int i = 0; i < D/4; ++i) {
            float4 q = eq[i];
            float4 v;
            float d0,d1,d2,d3;
            d0 = q.x - xr[4*i+0]; v.x = xr[4*i+0] + d0; dsum = fmaf(d0,d0,dsum);
            d1 = q.y - xr[4*i+1]; v.y = xr[4*i+1] + d1; dsum = fmaf(d1,d1,dsum);
            d2 = q.z - xr[4*i+2]; v.z = xr[4*i+2] + d2; dsum = fmaf(d2,d2,dsum);
            d3 = q.w - xr[4*i+3]; v.w = xr[4*i+3] + d3; dsum = fmaf(d3,d3,dsum);
            o[i] = v;
        }
    }

    out[IDX_OFF + r] = (float)bi;
    atomicAdd(&shist[bi], 1);

    // wave reduction of squared-diff, one global atomic per wave
    #pragma unroll
    for (int off = 32; off > 0; off >>= 1)
        dsum += __shfl_xor(dsum, off, 64);
    if ((threadIdx.x & 63) == 0)
        atomicAdd(wsum, dsum);

    __syncthreads();
    for (int i = threadIdx.x; i < K; i += TPB)
        if (shist[i]) atomicAdd(&whist[i], shist[i]);
}

__global__ __launch_bounds__(K) void vq_finalize(
    const float* __restrict__ wsum, const int* __restrict__ whist,
    float* __restrict__ out)
{
    __shared__ float red[K];
    int t = threadIdx.x;
    float c = (float)whist[t];
    float p = c / (float)NROWS;
    red[t] = p * logf(p + 1e-10f);
    __syncthreads();
    for (int s = K/2; s > 0; s >>= 1) {
        if (t < s) red[t] += red[t+s];
        __syncthreads();
    }
    if (t == 0) {
        out[PERP_OFF] = expf(-red[0]);
        out[LOSS_OFF] = 0.25f * (wsum[0] / (float)(NROWS*D));
    }
}

extern "C" void kernel_launch(void* const* d_in, const int* in_sizes, int n_in,
                              void* d_out, int out_size, void* d_ws, size_t ws_size,
                              hipStream_t stream)
{
    const float* x   = (const float*)d_in[0];
    const float* emb = (const float*)d_in[1];
    float* out   = (float*)d_out;
    float* wsum  = (float*)d_ws;                          // 1 float @ 0
    int*   whist = (int*)((char*)d_ws + 256);             // 512 ints @ 256B
    float* e2    = (float*)((char*)d_ws + 4096);          // 512 floats @ 4096B

    hipMemsetAsync(d_ws, 0, 4096, stream);                // zero wsum + hist
    vq_norms<<<K/64, 64, 0, stream>>>(emb, e2);
    vq_main<<<NBLOCKS, TPB, 0, stream>>>(x, emb, e2, out, wsum, whist);
    vq_finalize<<<1, K, 0, stream>>>(wsum, whist, out);
}

// Round 5
// 252.244 us; speedup vs baseline: 2.8650x; 2.8650x over previous
//
#include <hip/hip_runtime.h>

#define NROWS 131072          // 64*2048
#define D 64
#define K 512
#define TPB 256
#define ROWS_PER_BLOCK (TPB*2)        // 512
#define NBLOCKS (NROWS/ROWS_PER_BLOCK) // 256

#define LOSS_OFF (NROWS*D)    // 8388608
#define PERP_OFF (LOSS_OFF+1)
#define IDX_OFF  (LOSS_OFF+2)

// ws layout: [0]: float wsum; [256B]: int hist[512]; [4096B]: float e2[512]

__global__ __launch_bounds__(64) void vq_norms(
    const float* __restrict__ emb, float* __restrict__ e2)
{
    int k = blockIdx.x * 64 + threadIdx.x;   // grid 8 x 64
    const float* e = emb + (size_t)k * D;
    float s0=0.f,s1=0.f,s2=0.f,s3=0.f;
    #pragma unroll
    for (int d = 0; d < D; d += 4) {
        s0 = fmaf(e[d+0], e[d+0], s0);
        s1 = fmaf(e[d+1], e[d+1], s1);
        s2 = fmaf(e[d+2], e[d+2], s2);
        s3 = fmaf(e[d+3], e[d+3], s3);
    }
    e2[k] = (s0+s1)+(s2+s3);   // same order as rounds 1-4 (absmax 0.0)
}

// Broadcast element DD of lane-distributed code CV to all lanes (SGPR),
// feed both rows' accumulator chains. DD is compile-time.
#define RL(CV, DD) __int_as_float(__builtin_amdgcn_readlane(__float_as_int(CV), (DD)))

#define DOTCODE(CV, KK) do {                                        \
    float a0=0.f,a1=0.f,a2=0.f,a3=0.f;                              \
    float b0=0.f,b1=0.f,b2=0.f,b3=0.f;                              \
    _Pragma("unroll")                                               \
    for (int d = 0; d < D; d += 4) {                                \
        float e0 = RL(CV, d+0);                                     \
        float e1 = RL(CV, d+1);                                     \
        float e2v = RL(CV, d+2);                                    \
        float e3 = RL(CV, d+3);                                     \
        a0 = fmaf(xa[d+0], e0, a0);  b0 = fmaf(xb[d+0], e0, b0);    \
        a1 = fmaf(xa[d+1], e1, a1);  b1 = fmaf(xb[d+1], e1, b1);    \
        a2 = fmaf(xa[d+2], e2v, a2); b2 = fmaf(xb[d+2], e2v, b2);   \
        a3 = fmaf(xa[d+3], e3, a3);  b3 = fmaf(xb[d+3], e3, b3);    \
    }                                                               \
    float dotA = (a0+a1)+(a2+a3);                                   \
    float dotB = (b0+b1)+(b2+b3);                                   \
    float dA = fmaf(-2.f, dotA, e2n[(KK)]);                         \
    float dB = fmaf(-2.f, dotB, e2n[(KK)]);                         \
    if (dA < bestA) { bestA = dA; ia = (KK); }                      \
    if (dB < bestB) { bestB = dB; ib = (KK); }                      \
} while (0)

__global__ __launch_bounds__(TPB, 1) void vq_main(
    const float* __restrict__ x, const float* __restrict__ emb,
    const float* __restrict__ e2n,
    float* __restrict__ out, float* __restrict__ wsum, int* __restrict__ whist)
{
    __shared__ int shist[K];
    for (int i = threadIdx.x; i < K; i += TPB) shist[i] = 0;
    __syncthreads();

    const int r0 = blockIdx.x * ROWS_PER_BLOCK + threadIdx.x;
    const int r1 = r0 + TPB;
    const int lane = threadIdx.x & 63;

    // two rows into registers (R1's proven-clean shape: 128 floats, VGPR~156)
    float xa[D], xb[D];
    {
        const float4* pa = reinterpret_cast<const float4*>(x + (size_t)r0 * D);
        const float4* pb = reinterpret_cast<const float4*>(x + (size_t)r1 * D);
        #pragma unroll
        for (int i = 0; i < D/4; ++i) {
            float4 va = pa[i], vb = pb[i];
            xa[4*i+0]=va.x; xa[4*i+1]=va.y; xa[4*i+2]=va.z; xa[4*i+3]=va.w;
            xb[4*i+0]=vb.x; xb[4*i+1]=vb.y; xb[4*i+2]=vb.z; xb[4*i+3]=vb.w;
        }
    }

    // lane d holds element d of each staged code: 1 VGPR per code in flight
    const float* ecol = emb + lane;

    float bestA = 3.4e38f, bestB = 3.4e38f;
    int   ia = 0, ib = 0;

    float c0 = ecol[0*D], c1 = ecol[1*D], c2 = ecol[2*D], c3 = ecol[3*D];

    #pragma clang loop unroll(disable)
    for (int k = 0; k < K; k += 4) {
        DOTCODE(c0, k);
        { int kn = k+4; if (kn >= K) kn = 0; c0 = ecol[(size_t)kn * D]; }
        DOTCODE(c1, k+1);
        { int kn = k+5; if (kn >= K) kn = 0; c1 = ecol[(size_t)kn * D]; }
        DOTCODE(c2, k+2);
        { int kn = k+6; if (kn >= K) kn = 0; c2 = ecol[(size_t)kn * D]; }
        DOTCODE(c3, k+3);
        { int kn = k+7; if (kn >= K) kn = 0; c3 = ecol[(size_t)kn * D]; }
    }

    // epilogue: gather code from global (L2-hot), straight-through out,
    // squared-diff accumulation, index, histogram  (bit-identical to R1-4)
    float dsum = 0.f;
    {
        const float4* ea = reinterpret_cast<const float4*>(emb + (size_t)ia * D);
        const float4* eb = reinterpret_cast<const float4*>(emb + (size_t)ib * D);
        float4* oa = reinterpret_cast<float4*>(out + (size_t)r0 * D);
        float4* ob = reinterpret_cast<float4*>(out + (size_t)r1 * D);
        #pragma unroll
        for (int i = 0; i < D/4; ++i) {
            float4 qa = ea[i], qb = eb[i];
            float d0,d1,d2,d3;
            float4 va, vb;
            d0 = qa.x - xa[4*i+0]; va.x = xa[4*i+0] + d0; dsum = fmaf(d0,d0,dsum);
            d1 = qa.y - xa[4*i+1]; va.y = xa[4*i+1] + d1; dsum = fmaf(d1,d1,dsum);
            d2 = qa.z - xa[4*i+2]; va.z = xa[4*i+2] + d2; dsum = fmaf(d2,d2,dsum);
            d3 = qa.w - xa[4*i+3]; va.w = xa[4*i+3] + d3; dsum = fmaf(d3,d3,dsum);
            oa[i] = va;
            d0 = qb.x - xb[4*i+0]; vb.x = xb[4*i+0] + d0; dsum = fmaf(d0,d0,dsum);
            d1 = qb.y - xb[4*i+1]; vb.y = xb[4*i+1] + d1; dsum = fmaf(d1,d1,dsum);
            d2 = qb.z - xb[4*i+2]; vb.z = xb[4*i+2] + d2; dsum = fmaf(d2,d2,dsum);
            d3 = qb.w - xb[4*i+3]; vb.w = xb[4*i+3] + d3; dsum = fmaf(d3,d3,dsum);
            ob[i] = vb;
        }
    }

    out[IDX_OFF + r0] = (float)ia;
    out[IDX_OFF + r1] = (float)ib;

    atomicAdd(&shist[ia], 1);
    atomicAdd(&shist[ib], 1);

    // wave reduction of squared-diff, one global atomic per wave
    #pragma unroll
    for (int off = 32; off > 0; off >>= 1)
        dsum += __shfl_xor(dsum, off, 64);
    if ((threadIdx.x & 63) == 0)
        atomicAdd(wsum, dsum);

    __syncthreads();
    for (int i = threadIdx.x; i < K; i += TPB)
        if (shist[i]) atomicAdd(&whist[i], shist[i]);
}

__global__ __launch_bounds__(K) void vq_finalize(
    const float* __restrict__ wsum, const int* __restrict__ whist,
    float* __restrict__ out)
{
    __shared__ float red[K];
    int t = threadIdx.x;
    float c = (float)whist[t];
    float p = c / (float)NROWS;
    red[t] = p * logf(p + 1e-10f);
    __syncthreads();
    for (int s = K/2; s > 0; s >>= 1) {
        if (t < s) red[t] += red[t+s];
        __syncthreads();
    }
    if (t == 0) {
        out[PERP_OFF] = expf(-red[0]);
        out[LOSS_OFF] = 0.25f * (wsum[0] / (float)(NROWS*D));
    }
}

extern "C" void kernel_launch(void* const* d_in, const int* in_sizes, int n_in,
                              void* d_out, int out_size, void* d_ws, size_t ws_size,
                              hipStream_t stream)
{
    const float* x   = (const float*)d_in[0];
    const float* emb = (const float*)d_in[1];
    float* out   = (float*)d_out;
    float* wsum  = (float*)d_ws;                          // 1 float @ 0
    int*   whist = (int*)((char*)d_ws + 256);             // 512 ints @ 256B
    float* e2    = (float*)((char*)d_ws + 4096);          // 512 floats @ 4096B

    hipMemsetAsync(d_ws, 0, 4096, stream);                // zero wsum + hist
    vq_norms<<<K/64, 64, 0, stream>>>(emb, e2);
    vq_main<<<NBLOCKS, TPB, 0, stream>>>(x, emb, e2, out, wsum, whist);
    vq_finalize<<<1, K, 0, stream>>>(wsum, whist, out);
}